// Round 1
// baseline (666.383 us; speedup 1.0000x reference)
//
#include <hip/hip_runtime.h>

// Problem: X (64, 512, 4000) fp32; D=10, STRIDE=10 -> w=400.
// out[b,n,k] = X[b,n,10k+9] / X[b,n,10k] - 2.0f
// Rows are 4000 floats (divisible by 20), so each thread can own one
// 20-float group (2 output elements) without crossing row boundaries.
// HBM-bound: every 64B line of X contains a needed element, so min
// traffic ~524MB read + 52MB write.

__global__ __launch_bounds__(256) void ts_return_kernel(
    const float* __restrict__ X,
    float* __restrict__ out,
    int n_pairs)   // out_size / 2 = 6,553,600
{
    int j = blockIdx.x * blockDim.x + threadIdx.x;
    if (j >= n_pairs) return;

    const float* base = X + (size_t)j * 20;
    // group 2j:   first = base[0],  last = base[9]
    // group 2j+1: first = base[10], last = base[19]
    float x0  = base[0];
    float x9  = base[9];
    float x10 = base[10];
    float x19 = base[19];

    float2 r;
    r.x = x9  / x0  - 2.0f;
    r.y = x19 / x10 - 2.0f;
    // out index 2j is even -> 8B aligned float2 store
    reinterpret_cast<float2*>(out)[j] = r;
}

extern "C" void kernel_launch(void* const* d_in, const int* in_sizes, int n_in,
                              void* d_out, int out_size, void* d_ws, size_t ws_size,
                              hipStream_t stream) {
    const float* X = (const float*)d_in[0];
    float* out = (float*)d_out;

    int n_pairs = out_size / 2;
    int block = 256;
    int grid = (n_pairs + block - 1) / block;
    ts_return_kernel<<<grid, block, 0, stream>>>(X, out, n_pairs);
}